// Round 1
// baseline (1297.978 us; speedup 1.0000x reference)
//
#include <hip/hip_runtime.h>
#include <hip/hip_bf16.h>
#include <stdint.h>

#define T_TOK 4096
#define DDIM  2048
#define HDIM  2048
#define NEXP  8
#define KSEL  4
#define NPAIR (T_TOK * KSEL)

typedef __attribute__((ext_vector_type(8))) short bf16x8;
typedef __attribute__((ext_vector_type(4))) float f32x4;
typedef __attribute__((ext_vector_type(4))) unsigned short u16x4v;

__device__ inline unsigned short f2bf(float f) {
  unsigned u = __builtin_bit_cast(unsigned, f);
  unsigned r = (u + 0x7fffu + ((u >> 16) & 1u)) >> 16;
  return (unsigned short)r;
}

// ---------------- convert x (fp32) -> bf16 ----------------
__global__ __launch_bounds__(256) void conv_x_kernel(const float* __restrict__ in,
                                                     unsigned short* __restrict__ out) {
  int i = blockIdx.x * 256 + threadIdx.x;  // 4 elems per thread
  float4 v = ((const float4*)in)[i];
  u16x4v o;
  o[0] = f2bf(v.x); o[1] = f2bf(v.y); o[2] = f2bf(v.z); o[3] = f2bf(v.w);
  ((u16x4v*)out)[i] = o;
}

// ---------------- transpose + convert: [E][R=2048][C=2048] fp32 -> [E][C][R] bf16 ----------------
__global__ __launch_bounds__(256) void transpose_conv_kernel(const float* __restrict__ in,
                                                             unsigned short* __restrict__ out) {
  __shared__ float tile[32][33];
  int e = blockIdx.z;
  const float* src = in + (size_t)e * DDIM * HDIM;
  unsigned short* dst = out + (size_t)e * DDIM * HDIM;
  int c0 = blockIdx.x * 32, r0 = blockIdx.y * 32;
  int tx = threadIdx.x, ty = threadIdx.y;  // block (32,8)
#pragma unroll
  for (int i = 0; i < 4; ++i)
    tile[ty + i * 8][tx] = src[(size_t)(r0 + ty + i * 8) * 2048 + c0 + tx];
  __syncthreads();
#pragma unroll
  for (int i = 0; i < 4; ++i)
    dst[(size_t)(c0 + ty + i * 8) * 2048 + r0 + tx] = f2bf(tile[tx][ty + i * 8]);
}

// ---------------- routing: logits (fp32, to d_out), top-4, renorm weights, expert counts ----------------
__global__ __launch_bounds__(256) void routing_kernel(const float* __restrict__ x,
                                                      const float* __restrict__ Wg,
                                                      const float* __restrict__ bg,
                                                      float* __restrict__ logits,
                                                      float* __restrict__ rw,
                                                      int* __restrict__ sel,
                                                      int* __restrict__ cnt) {
  int t = blockIdx.x * 4 + (threadIdx.x >> 6);  // one wave per token
  int l = threadIdx.x & 63;
  const float* xr = x + (size_t)t * DDIM;
  float acc[8] = {0.f, 0.f, 0.f, 0.f, 0.f, 0.f, 0.f, 0.f};
  for (int i = 0; i < DDIM / 64; ++i) {
    int d = i * 64 + l;
    float xv = xr[d];
    float4 w0 = *(const float4*)(Wg + (size_t)d * 8);
    float4 w1 = *(const float4*)(Wg + (size_t)d * 8 + 4);
    acc[0] = fmaf(xv, w0.x, acc[0]); acc[1] = fmaf(xv, w0.y, acc[1]);
    acc[2] = fmaf(xv, w0.z, acc[2]); acc[3] = fmaf(xv, w0.w, acc[3]);
    acc[4] = fmaf(xv, w1.x, acc[4]); acc[5] = fmaf(xv, w1.y, acc[5]);
    acc[6] = fmaf(xv, w1.z, acc[6]); acc[7] = fmaf(xv, w1.w, acc[7]);
  }
#pragma unroll
  for (int e = 0; e < 8; ++e)
#pragma unroll
    for (int off = 32; off > 0; off >>= 1) acc[e] += __shfl_down(acc[e], off);
  if (l == 0) {
    float lg[8];
#pragma unroll
    for (int e = 0; e < 8; ++e) {
      lg[e] = acc[e] + bg[e];
      logits[(size_t)t * 8 + e] = lg[e];
    }
    float mx = lg[0];
#pragma unroll
    for (int e = 1; e < 8; ++e) mx = fmaxf(mx, lg[e]);
    float p[8];
#pragma unroll
    for (int e = 0; e < 8; ++e) p[e] = expf(lg[e] - mx);
    bool used[8] = {false, false, false, false, false, false, false, false};
    float wsum = 0.f; int se[4]; float pv[4];
    for (int k = 0; k < 4; ++k) {
      int best = 0; float bv = -1.f;
      for (int e = 0; e < 8; ++e)
        if (!used[e] && p[e] > bv) { bv = p[e]; best = e; }
      used[best] = true; se[k] = best; pv[k] = bv; wsum += bv;
    }
    for (int k = 0; k < 4; ++k) {
      rw[t * 4 + k] = pv[k] / wsum;
      sel[t * 4 + k] = se[k];
      atomicAdd(&cnt[se[k]], 1);
    }
  }
}

__global__ void offsets_kernel(const int* __restrict__ cnt, int* __restrict__ off) {
  if (threadIdx.x == 0) {
    int s = 0;
    for (int e = 0; e < NEXP; ++e) { off[e] = s; s += cnt[e]; }
  }
}

__global__ __launch_bounds__(256) void scatter_kernel(const int* __restrict__ sel,
                                                      const float* __restrict__ rw,
                                                      const int* __restrict__ off,
                                                      int* __restrict__ fill,
                                                      int* __restrict__ tok,
                                                      float* __restrict__ wof) {
  int t = blockIdx.x * 256 + threadIdx.x;
  for (int k = 0; k < 4; ++k) {
    int e = sel[t * 4 + k];
    int slot = atomicAdd(&fill[e], 1);
    int p = off[e] + slot;
    tok[p] = t;
    wof[p] = rw[t * 4 + k];
  }
}

// ---------------- MoE GEMM: C[m,n] = A[m,:2048] * Bt[e][n,:2048]^T ----------------
// MODE 0: A rows gathered via tok[]; epilogue = gelu(acc + b1) -> hout (bf16)
// MODE 1: A rows = contiguous pair rows of h; epilogue = atomicAdd(out[tok[p]], wof[p]*(acc + b2))
#define GLL(g, l) __builtin_amdgcn_global_load_lds(                         \
    (const __attribute__((address_space(1))) void*)(g),                    \
    (__attribute__((address_space(3))) void*)(l), 16, 0, 0)

template <int MODE>
__global__ __launch_bounds__(256) void moe_gemm_kernel(
    const unsigned short* __restrict__ A, const unsigned short* __restrict__ Bt,
    const float* __restrict__ bias, const int* __restrict__ cnt,
    const int* __restrict__ off, const int* __restrict__ tok,
    const float* __restrict__ wof, unsigned short* __restrict__ hout,
    float* __restrict__ out) {
  __shared__ unsigned short Alds[128 * 32];
  __shared__ unsigned short Blds[128 * 32];
  const int e = blockIdx.z;
  const int ne = cnt[e];
  const int m0 = blockIdx.x * 128;
  if (m0 >= ne) return;
  const int oe = off[e];
  const int n0 = blockIdx.y * 128;
  const int tid = threadIdx.x;
  const int w = tid >> 6;
  const int l = tid & 63;

  // staging mapping: thread stages rows (tid/4) and (64 + tid/4), 16B each, 2 calls per tile
  const int r0 = tid >> 2;
  const int ce = (tid & 3) * 8;  // element offset within row
  int pr0 = m0 + r0;       if (pr0 > ne - 1) pr0 = ne - 1;
  int pr1 = m0 + 64 + r0;  if (pr1 > ne - 1) pr1 = ne - 1;
  const unsigned short *gA0, *gA1;
  if (MODE == 0) {
    gA0 = A + (size_t)tok[oe + pr0] * 2048 + ce;
    gA1 = A + (size_t)tok[oe + pr1] * 2048 + ce;
  } else {
    gA0 = A + (size_t)(oe + pr0) * 2048 + ce;
    gA1 = A + (size_t)(oe + pr1) * 2048 + ce;
  }
  const unsigned short* gB0 = Bt + ((size_t)e * 2048 + n0 + r0) * 2048 + ce;
  const unsigned short* gB1 = gB0 + (size_t)64 * 2048;
  unsigned short* lA0 = Alds + w * 512;
  unsigned short* lA1 = Alds + 2048 + w * 512;
  unsigned short* lB0 = Blds + w * 512;
  unsigned short* lB1 = Blds + 2048 + w * 512;

  const int wr = (w >> 1) * 64;  // wave row offset in 128x128 tile
  const int wc = (w & 1) * 64;   // wave col offset
  const int lr = l & 15;
  const int lk = (l >> 4) * 8;

  f32x4 acc[4][4];
#pragma unroll
  for (int m = 0; m < 4; ++m)
#pragma unroll
    for (int n = 0; n < 4; ++n) acc[m][n] = (f32x4){0.f, 0.f, 0.f, 0.f};

  for (int k0 = 0; k0 < 2048; k0 += 32) {
    GLL(gA0 + k0, lA0);
    GLL(gA1 + k0, lA1);
    GLL(gB0 + k0, lB0);
    GLL(gB1 + k0, lB1);
    __syncthreads();
    bf16x8 af[4], bfg[4];
#pragma unroll
    for (int m = 0; m < 4; ++m)
      af[m] = *(const bf16x8*)&Alds[(wr + m * 16 + lr) * 32 + lk];
#pragma unroll
    for (int n = 0; n < 4; ++n)
      bfg[n] = *(const bf16x8*)&Blds[(wc + n * 16 + lr) * 32 + lk];
#pragma unroll
    for (int m = 0; m < 4; ++m)
#pragma unroll
      for (int n = 0; n < 4; ++n)
        acc[m][n] = __builtin_amdgcn_mfma_f32_16x16x32_bf16(af[m], bfg[n], acc[m][n], 0, 0, 0);
    __syncthreads();
  }

  // epilogue: C/D layout col = lane&15, row = (lane>>4)*4 + j
  const int rj = (l >> 4) * 4;
#pragma unroll
  for (int m = 0; m < 4; ++m) {
    const int rb = wr + m * 16 + rj;
#pragma unroll
    for (int n = 0; n < 4; ++n) {
      const int col = n0 + wc + n * 16 + lr;
      const float b = bias[e * 2048 + col];
#pragma unroll
      for (int j = 0; j < 4; ++j) {
        const int row = m0 + rb + j;
        if (row < ne) {
          float v = acc[m][n][j] + b;
          if (MODE == 0) {
            float g = 0.5f * v * (1.0f + erff(v * 0.70710678118f));
            hout[(size_t)(oe + row) * 2048 + col] = f2bf(g);
          } else {
            const int p = oe + row;
            atomicAdd(&out[(size_t)tok[p] * 2048 + col], wof[p] * v);
          }
        }
      }
    }
  }
}

extern "C" void kernel_launch(void* const* d_in, const int* in_sizes, int n_in,
                              void* d_out, int out_size, void* d_ws, size_t ws_size,
                              hipStream_t stream) {
  const float* x  = (const float*)d_in[0];
  const float* Wg = (const float*)d_in[1];
  const float* bg = (const float*)d_in[2];
  const float* W1 = (const float*)d_in[3];
  const float* b1 = (const float*)d_in[4];
  const float* W2 = (const float*)d_in[5];
  const float* b2 = (const float*)d_in[6];
  float* out = (float*)d_out;
  float* logits = out + (size_t)T_TOK * DDIM;

  char* ws = (char*)d_ws;
  int* cnt  = (int*)(ws);
  int* off  = (int*)(ws + 32);
  int* fill = (int*)(ws + 64);
  size_t o = 256;
  unsigned short* xb   = (unsigned short*)(ws + o); o += (size_t)T_TOK * DDIM * 2;
  unsigned short* W1t  = (unsigned short*)(ws + o); o += (size_t)NEXP * DDIM * HDIM * 2;
  unsigned short* W2t  = (unsigned short*)(ws + o); o += (size_t)NEXP * DDIM * HDIM * 2;
  unsigned short* hbuf = (unsigned short*)(ws + o); o += (size_t)NPAIR * HDIM * 2;
  float* rw  = (float*)(ws + o); o += (size_t)T_TOK * 4 * 4;
  int*   sel = (int*)(ws + o);   o += (size_t)T_TOK * 4 * 4;
  int*   tok = (int*)(ws + o);   o += (size_t)NPAIR * 4;
  float* wof = (float*)(ws + o); o += (size_t)NPAIR * 4;

  hipMemsetAsync(d_out, 0, (size_t)T_TOK * DDIM * sizeof(float), stream);
  hipMemsetAsync(ws, 0, 256, stream);

  conv_x_kernel<<<(T_TOK * DDIM) / 1024, 256, 0, stream>>>(x, xb);
  transpose_conv_kernel<<<dim3(64, 64, 8), dim3(32, 8), 0, stream>>>(W1, W1t);
  transpose_conv_kernel<<<dim3(64, 64, 8), dim3(32, 8), 0, stream>>>(W2, W2t);
  routing_kernel<<<T_TOK / 4, 256, 0, stream>>>(x, Wg, bg, logits, rw, sel, cnt);
  offsets_kernel<<<1, 64, 0, stream>>>(cnt, off);
  scatter_kernel<<<T_TOK / 256, 256, 0, stream>>>(sel, rw, off, fill, tok, wof);

  moe_gemm_kernel<0><<<dim3(32, 16, 8), 256, 0, stream>>>(xb, W1t, b1, cnt, off, tok, wof, hbuf, nullptr);
  moe_gemm_kernel<1><<<dim3(32, 16, 8), 256, 0, stream>>>(hbuf, W2t, b2, cnt, off, tok, wof, nullptr, out);
}

// Round 2
// 895.270 us; speedup vs baseline: 1.4498x; 1.4498x over previous
//
#include <hip/hip_runtime.h>
#include <hip/hip_bf16.h>
#include <stdint.h>

#define T_TOK 4096
#define DDIM  2048
#define HDIM  2048
#define NEXP  8
#define NPAIR (T_TOK * 4)
#define NT    (DDIM / 64)   // 32 K-tiles of 64

typedef __attribute__((ext_vector_type(8))) short bf16x8;
typedef __attribute__((ext_vector_type(4))) float f32x4;
typedef __attribute__((ext_vector_type(4))) unsigned short u16x4v;

__device__ inline unsigned short f2bf(float f) {
  unsigned u = __builtin_bit_cast(unsigned, f);
  unsigned r = (u + 0x7fffu + ((u >> 16) & 1u)) >> 16;
  return (unsigned short)r;
}

// ---------------- convert x (fp32) -> bf16 ----------------
__global__ __launch_bounds__(256) void conv_x_kernel(const float* __restrict__ in,
                                                     unsigned short* __restrict__ out) {
  int i = blockIdx.x * 256 + threadIdx.x;  // 4 elems per thread
  float4 v = ((const float4*)in)[i];
  u16x4v o;
  o[0] = f2bf(v.x); o[1] = f2bf(v.y); o[2] = f2bf(v.z); o[3] = f2bf(v.w);
  ((u16x4v*)out)[i] = o;
}

// ------- transpose + convert: [E][R=2048][C=2048] fp32 -> [E][C][R] bf16, 64x64 tiles -------
__global__ __launch_bounds__(256) void transpose_conv_kernel(const float* __restrict__ in,
                                                             unsigned short* __restrict__ out) {
  __shared__ float tile[64][65];
  int e = blockIdx.z;
  const float* src = in + (size_t)e * DDIM * HDIM;
  unsigned short* dst = out + (size_t)e * DDIM * HDIM;
  int c0 = blockIdx.x * 64, r0 = blockIdx.y * 64;
  int tid = threadIdx.x;
  int lrow = tid >> 5, lc2 = tid & 31;
#pragma unroll
  for (int i = 0; i < 8; ++i) {
    float2 v = *(const float2*)(src + (size_t)(r0 + lrow + i * 8) * 2048 + c0 + lc2 * 2);
    tile[lrow + i * 8][lc2 * 2] = v.x;
    tile[lrow + i * 8][lc2 * 2 + 1] = v.y;
  }
  __syncthreads();
  int srow = tid >> 5, sp = tid & 31;
#pragma unroll
  for (int i = 0; i < 8; ++i) {
    int c = srow + i * 8;
    ushort2 o;
    o.x = f2bf(tile[sp * 2][c]);
    o.y = f2bf(tile[sp * 2 + 1][c]);
    *(ushort2*)(dst + (size_t)(c0 + c) * 2048 + r0 + sp * 2) = o;
  }
}

// ---------------- routing ----------------
__global__ __launch_bounds__(256) void routing_kernel(const float* __restrict__ x,
                                                      const float* __restrict__ Wg,
                                                      const float* __restrict__ bg,
                                                      float* __restrict__ logits,
                                                      float* __restrict__ rw,
                                                      int* __restrict__ sel,
                                                      int* __restrict__ cnt) {
  int t = blockIdx.x * 4 + (threadIdx.x >> 6);  // one wave per token
  int l = threadIdx.x & 63;
  const float* xr = x + (size_t)t * DDIM;
  float acc[8] = {0.f, 0.f, 0.f, 0.f, 0.f, 0.f, 0.f, 0.f};
  for (int i = 0; i < DDIM / 64; ++i) {
    int d = i * 64 + l;
    float xv = xr[d];
    float4 w0 = *(const float4*)(Wg + (size_t)d * 8);
    float4 w1 = *(const float4*)(Wg + (size_t)d * 8 + 4);
    acc[0] = fmaf(xv, w0.x, acc[0]); acc[1] = fmaf(xv, w0.y, acc[1]);
    acc[2] = fmaf(xv, w0.z, acc[2]); acc[3] = fmaf(xv, w0.w, acc[3]);
    acc[4] = fmaf(xv, w1.x, acc[4]); acc[5] = fmaf(xv, w1.y, acc[5]);
    acc[6] = fmaf(xv, w1.z, acc[6]); acc[7] = fmaf(xv, w1.w, acc[7]);
  }
#pragma unroll
  for (int e = 0; e < 8; ++e)
#pragma unroll
    for (int off = 32; off > 0; off >>= 1) acc[e] += __shfl_down(acc[e], off);
  if (l == 0) {
    float lg[8];
#pragma unroll
    for (int e = 0; e < 8; ++e) {
      lg[e] = acc[e] + bg[e];
      logits[(size_t)t * 8 + e] = lg[e];
    }
    float mx = lg[0];
#pragma unroll
    for (int e = 1; e < 8; ++e) mx = fmaxf(mx, lg[e]);
    float p[8];
#pragma unroll
    for (int e = 0; e < 8; ++e) p[e] = expf(lg[e] - mx);
    bool used[8] = {false, false, false, false, false, false, false, false};
    float wsum = 0.f; int se[4]; float pv[4];
    for (int k = 0; k < 4; ++k) {
      int best = 0; float bv = -1.f;
      for (int e = 0; e < 8; ++e)
        if (!used[e] && p[e] > bv) { bv = p[e]; best = e; }
      used[best] = true; se[k] = best; pv[k] = bv; wsum += bv;
    }
    for (int k = 0; k < 4; ++k) {
      rw[t * 4 + k] = pv[k] / wsum;
      sel[t * 4 + k] = se[k];
      atomicAdd(&cnt[se[k]], 1);
    }
  }
}

__global__ void offsets_kernel(const int* __restrict__ cnt, int* __restrict__ off) {
  if (threadIdx.x == 0) {
    int s = 0;
    for (int e = 0; e < NEXP; ++e) { off[e] = s; s += cnt[e]; }
  }
}

__global__ __launch_bounds__(256) void scatter_kernel(const int* __restrict__ sel,
                                                      const float* __restrict__ rw,
                                                      const int* __restrict__ off,
                                                      int* __restrict__ fill,
                                                      int* __restrict__ tok,
                                                      float* __restrict__ wof) {
  int t = blockIdx.x * 256 + threadIdx.x;
  for (int k = 0; k < 4; ++k) {
    int e = sel[t * 4 + k];
    int slot = atomicAdd(&fill[e], 1);
    int p = off[e] + slot;
    tok[p] = t;
    wof[p] = rw[t * 4 + k];
  }
}

// ---------------- MoE GEMM: 256x256 tile, BK=64, 8 waves, counted-vmcnt double buffer ----------------
#define GLL(g, l) __builtin_amdgcn_global_load_lds(                         \
    (const __attribute__((address_space(1))) void*)(g),                    \
    (__attribute__((address_space(3))) void*)(l), 16, 0, 0)

template <int MODE>
__global__ __launch_bounds__(512, 2) void moe_gemm_kernel(
    const unsigned short* __restrict__ A, const unsigned short* __restrict__ Bt,
    const float* __restrict__ bias, const int* __restrict__ cnt,
    const int* __restrict__ off, const int* __restrict__ tok,
    const float* __restrict__ wof, unsigned short* __restrict__ hout,
    float* __restrict__ out) {
  __shared__ unsigned short lds[65536];  // 128 KiB: [2 buf][A 32KB | B 32KB]
  const int bid = blockIdx.x;
  const int e   = bid & 7;        // expert == XCD (T1)
  const int rem = bid >> 3;
  const int bm  = rem & 15;
  const int bn  = rem >> 4;
  const int ne  = cnt[e];
  const int m0  = bm * 256;
  if (m0 >= ne) return;
  const int oe  = off[e];
  const int n0  = bn * 256;
  const int tid = threadIdx.x;
  const int w   = tid >> 6;
  const int l   = tid & 63;

  // staging: thread stages 4 A rows + 4 B rows (16B each) per K-tile.
  // LDS stays linear; global source chunk is XOR-swizzled (T2 both-sides, rule #21):
  // LDS slot (row, s) holds global chunk s ^ (row&7).
  const int srow = tid >> 3;                       // row within a 64-row round
  const int scg  = ((tid & 7) ^ (srow & 7)) * 8;   // swizzled source chunk, elems
  const unsigned short* aP[4];
  const unsigned short* bP[4];
#pragma unroll
  for (int j = 0; j < 4; ++j) {
    int r = m0 + j * 64 + srow;
    if (r > ne - 1) r = ne - 1;
    if (MODE == 0)
      aP[j] = A + (size_t)tok[oe + r] * 2048 + scg;
    else
      aP[j] = A + (size_t)(oe + r) * 2048 + scg;
    bP[j] = Bt + ((size_t)e * 2048 + n0 + j * 64 + srow) * 2048 + scg;
  }
  char* ldsc = (char*)lds;

  const int wr = (w >> 2) * 128;  // 2 waves in M
  const int wc = (w & 3) * 64;    // 4 waves in N
  const int lr = l & 15;
  const int lq = l >> 4;
  const int swz = lr & 7;

  f32x4 acc[8][4];
#pragma unroll
  for (int m = 0; m < 8; ++m)
#pragma unroll
    for (int n = 0; n < 4; ++n) acc[m][n] = (f32x4){0.f, 0.f, 0.f, 0.f};

  // prologue: stage tile 0 -> buf 0
#pragma unroll
  for (int j = 0; j < 4; ++j) GLL(aP[j], ldsc + j * 8192 + w * 1024);
#pragma unroll
  for (int j = 0; j < 4; ++j) GLL(bP[j], ldsc + 32768 + j * 8192 + w * 1024);

#pragma unroll 1
  for (int t = 0; t < NT; ++t) {
    if (t < NT - 1) {
      // issue next tile's 8 loads into the other buffer
      const int kOff = (t + 1) * 64;
      char* dstA = ldsc + ((t + 1) & 1) * 65536;
#pragma unroll
      for (int j = 0; j < 4; ++j) GLL(aP[j] + kOff, dstA + j * 8192 + w * 1024);
#pragma unroll
      for (int j = 0; j < 4; ++j) GLL(bP[j] + kOff, dstA + 32768 + j * 8192 + w * 1024);
      // counted wait: tile t's 8 loads retired (in-order), tile t+1's stay in flight
      asm volatile("s_waitcnt vmcnt(8)" ::: "memory");
    } else {
      asm volatile("s_waitcnt vmcnt(0)" ::: "memory");
    }
    __builtin_amdgcn_s_barrier();   // all waves' tile-t loads landed
    asm volatile("" ::: "memory");

    const unsigned short* Ab = lds + (t & 1) * 32768;  // shorts
    const unsigned short* Bb = Ab + 16384;
#pragma unroll
    for (int kk = 0; kk < 2; ++kk) {
      bf16x8 af[8], bfr[4];
#pragma unroll
      for (int m = 0; m < 8; ++m)
        af[m] = *(const bf16x8*)&Ab[(wr + m * 16 + lr) * 64 + ((kk * 4 + lq) ^ swz) * 8];
#pragma unroll
      for (int n = 0; n < 4; ++n)
        bfr[n] = *(const bf16x8*)&Bb[(wc + n * 16 + lr) * 64 + ((kk * 4 + lq) ^ swz) * 8];
      __builtin_amdgcn_s_setprio(1);
#pragma unroll
      for (int m = 0; m < 8; ++m)
#pragma unroll
        for (int n = 0; n < 4; ++n)
          acc[m][n] = __builtin_amdgcn_mfma_f32_16x16x32_bf16(af[m], bfr[n], acc[m][n], 0, 0, 0);
      __builtin_amdgcn_s_setprio(0);
    }
    asm volatile("" ::: "memory");
    __builtin_amdgcn_s_barrier();   // safe to overwrite buf[t&1] next iter
    asm volatile("" ::: "memory");
  }

  // epilogue: C/D layout col = lane&15, row = (lane>>4)*4 + j
  const int rj = lq * 4;
  float bvn[4];
#pragma unroll
  for (int n = 0; n < 4; ++n) bvn[n] = bias[e * 2048 + n0 + wc + n * 16 + lr];
#pragma unroll
  for (int m = 0; m < 8; ++m) {
    const int rbase = m0 + wr + m * 16 + rj;
#pragma unroll
    for (int j = 0; j < 4; ++j) {
      const int row = rbase + j;
      if (row < ne) {
        if (MODE == 0) {
#pragma unroll
          for (int n = 0; n < 4; ++n) {
            const int col = n0 + wc + n * 16 + lr;
            float v = acc[m][n][j] + bvn[n];
            float g = 0.5f * v * (1.0f + erff(v * 0.70710678118f));
            hout[(size_t)(oe + row) * 2048 + col] = f2bf(g);
          }
        } else {
          const int p = oe + row;
          const int tk = tok[p];
          const float wf = wof[p];
#pragma unroll
          for (int n = 0; n < 4; ++n) {
            const int col = n0 + wc + n * 16 + lr;
            atomicAdd(&out[(size_t)tk * 2048 + col], wf * (acc[m][n][j] + bvn[n]));
          }
        }
      }
    }
  }
}

extern "C" void kernel_launch(void* const* d_in, const int* in_sizes, int n_in,
                              void* d_out, int out_size, void* d_ws, size_t ws_size,
                              hipStream_t stream) {
  const float* x  = (const float*)d_in[0];
  const float* Wg = (const float*)d_in[1];
  const float* bg = (const float*)d_in[2];
  const float* W1 = (const float*)d_in[3];
  const float* b1 = (const float*)d_in[4];
  const float* W2 = (const float*)d_in[5];
  const float* b2 = (const float*)d_in[6];
  float* out = (float*)d_out;
  float* logits = out + (size_t)T_TOK * DDIM;

  char* ws = (char*)d_ws;
  int* cnt  = (int*)(ws);
  int* off  = (int*)(ws + 32);
  int* fill = (int*)(ws + 64);
  size_t o = 256;
  unsigned short* xb   = (unsigned short*)(ws + o); o += (size_t)T_TOK * DDIM * 2;
  unsigned short* W1t  = (unsigned short*)(ws + o); o += (size_t)NEXP * DDIM * HDIM * 2;
  unsigned short* W2t  = (unsigned short*)(ws + o); o += (size_t)NEXP * DDIM * HDIM * 2;
  unsigned short* hbuf = (unsigned short*)(ws + o); o += (size_t)NPAIR * HDIM * 2;
  float* rw  = (float*)(ws + o); o += (size_t)T_TOK * 4 * 4;
  int*   sel = (int*)(ws + o);   o += (size_t)T_TOK * 4 * 4;
  int*   tok = (int*)(ws + o);   o += (size_t)NPAIR * 4;
  float* wof = (float*)(ws + o); o += (size_t)NPAIR * 4;

  hipMemsetAsync(d_out, 0, (size_t)T_TOK * DDIM * sizeof(float), stream);
  hipMemsetAsync(ws, 0, 256, stream);

  conv_x_kernel<<<(T_TOK * DDIM) / 1024, 256, 0, stream>>>(x, xb);
  transpose_conv_kernel<<<dim3(32, 32, 8), 256, 0, stream>>>(W1, W1t);
  transpose_conv_kernel<<<dim3(32, 32, 8), 256, 0, stream>>>(W2, W2t);
  routing_kernel<<<T_TOK / 4, 256, 0, stream>>>(x, Wg, bg, logits, rw, sel, cnt);
  offsets_kernel<<<1, 64, 0, stream>>>(cnt, off);
  scatter_kernel<<<T_TOK / 256, 256, 0, stream>>>(sel, rw, off, fill, tok, wof);

  moe_gemm_kernel<0><<<dim3(1024), 512, 0, stream>>>(xb, W1t, b1, cnt, off, tok, wof, hbuf, nullptr);
  moe_gemm_kernel<1><<<dim3(1024), 512, 0, stream>>>(hbuf, W2t, b2, cnt, off, tok, wof, nullptr, out);
}

// Round 4
// 855.265 us; speedup vs baseline: 1.5176x; 1.0468x over previous
//
#include <hip/hip_runtime.h>
#include <hip/hip_bf16.h>
#include <stdint.h>

#define T_TOK 4096
#define DDIM  2048
#define HDIM  2048
#define NEXP  8
#define NPAIR (T_TOK * 4)
#define NT    (DDIM / 64)   // 32 K-tiles of 64
#define NITER (NT / 2)      // 16 iterations, 2 K-tiles each

typedef __attribute__((ext_vector_type(8))) short bf16x8;
typedef __attribute__((ext_vector_type(4))) float f32x4;
typedef __attribute__((ext_vector_type(4))) unsigned short u16x4v;

__device__ inline unsigned short f2bf(float f) {
  unsigned u = __builtin_bit_cast(unsigned, f);
  unsigned r = (u + 0x7fffu + ((u >> 16) & 1u)) >> 16;
  return (unsigned short)r;
}

// ---------------- convert x (fp32) -> bf16 ----------------
__global__ __launch_bounds__(256) void conv_x_kernel(const float* __restrict__ in,
                                                     unsigned short* __restrict__ out) {
  int i = blockIdx.x * 256 + threadIdx.x;  // 4 elems per thread
  float4 v = ((const float4*)in)[i];
  u16x4v o;
  o[0] = f2bf(v.x); o[1] = f2bf(v.y); o[2] = f2bf(v.z); o[3] = f2bf(v.w);
  ((u16x4v*)out)[i] = o;
}

// ------- transpose + convert: [E][R=2048][C=2048] fp32 -> [E][C][R] bf16, 64x64 tiles -------
__global__ __launch_bounds__(256) void transpose_conv_kernel(const float* __restrict__ in,
                                                             unsigned short* __restrict__ out) {
  __shared__ float tile[64][65];
  int e = blockIdx.z;
  const float* src = in + (size_t)e * DDIM * HDIM;
  unsigned short* dst = out + (size_t)e * DDIM * HDIM;
  int c0 = blockIdx.x * 64, r0 = blockIdx.y * 64;
  int tid = threadIdx.x;
  int lrow = tid >> 5, lc2 = tid & 31;
#pragma unroll
  for (int i = 0; i < 8; ++i) {
    float2 v = *(const float2*)(src + (size_t)(r0 + lrow + i * 8) * 2048 + c0 + lc2 * 2);
    tile[lrow + i * 8][lc2 * 2] = v.x;
    tile[lrow + i * 8][lc2 * 2 + 1] = v.y;
  }
  __syncthreads();
  int srow = tid >> 5, sp = tid & 31;
#pragma unroll
  for (int i = 0; i < 8; ++i) {
    int c = srow + i * 8;
    ushort2 o;
    o.x = f2bf(tile[sp * 2][c]);
    o.y = f2bf(tile[sp * 2 + 1][c]);
    *(ushort2*)(dst + (size_t)(c0 + c) * 2048 + r0 + sp * 2) = o;
  }
}

// ---------------- routing ----------------
__global__ __launch_bounds__(256) void routing_kernel(const float* __restrict__ x,
                                                      const float* __restrict__ Wg,
                                                      const float* __restrict__ bg,
                                                      float* __restrict__ logits,
                                                      float* __restrict__ rw,
                                                      int* __restrict__ sel,
                                                      int* __restrict__ cnt) {
  int t = blockIdx.x * 4 + (threadIdx.x >> 6);  // one wave per token
  int l = threadIdx.x & 63;
  const float* xr = x + (size_t)t * DDIM;
  float acc[8] = {0.f, 0.f, 0.f, 0.f, 0.f, 0.f, 0.f, 0.f};
  for (int i = 0; i < DDIM / 64; ++i) {
    int d = i * 64 + l;
    float xv = xr[d];
    float4 w0 = *(const float4*)(Wg + (size_t)d * 8);
    float4 w1 = *(const float4*)(Wg + (size_t)d * 8 + 4);
    acc[0] = fmaf(xv, w0.x, acc[0]); acc[1] = fmaf(xv, w0.y, acc[1]);
    acc[2] = fmaf(xv, w0.z, acc[2]); acc[3] = fmaf(xv, w0.w, acc[3]);
    acc[4] = fmaf(xv, w1.x, acc[4]); acc[5] = fmaf(xv, w1.y, acc[5]);
    acc[6] = fmaf(xv, w1.z, acc[6]); acc[7] = fmaf(xv, w1.w, acc[7]);
  }
#pragma unroll
  for (int e = 0; e < 8; ++e)
#pragma unroll
    for (int off = 32; off > 0; off >>= 1) acc[e] += __shfl_down(acc[e], off);
  if (l == 0) {
    float lg[8];
#pragma unroll
    for (int e = 0; e < 8; ++e) {
      lg[e] = acc[e] + bg[e];
      logits[(size_t)t * 8 + e] = lg[e];
    }
    float mx = lg[0];
#pragma unroll
    for (int e = 1; e < 8; ++e) mx = fmaxf(mx, lg[e]);
    float p[8];
#pragma unroll
    for (int e = 0; e < 8; ++e) p[e] = expf(lg[e] - mx);
    bool used[8] = {false, false, false, false, false, false, false, false};
    float wsum = 0.f; int se[4]; float pv[4];
    for (int k = 0; k < 4; ++k) {
      int best = 0; float bv = -1.f;
      for (int e = 0; e < 8; ++e)
        if (!used[e] && p[e] > bv) { bv = p[e]; best = e; }
      used[best] = true; se[k] = best; pv[k] = bv; wsum += bv;
    }
    for (int k = 0; k < 4; ++k) {
      rw[t * 4 + k] = pv[k] / wsum;
      sel[t * 4 + k] = se[k];
      atomicAdd(&cnt[se[k]], 1);
    }
  }
}

__global__ void offsets_kernel(const int* __restrict__ cnt, int* __restrict__ off) {
  if (threadIdx.x == 0) {
    int s = 0;
    for (int e = 0; e < NEXP; ++e) { off[e] = s; s += cnt[e]; }
  }
}

__global__ __launch_bounds__(256) void scatter_kernel(const int* __restrict__ sel,
                                                      const float* __restrict__ rw,
                                                      const int* __restrict__ off,
                                                      int* __restrict__ fill,
                                                      int* __restrict__ tok,
                                                      float* __restrict__ wof) {
  int t = blockIdx.x * 256 + threadIdx.x;
  for (int k = 0; k < 4; ++k) {
    int e = sel[t * 4 + k];
    int slot = atomicAdd(&fill[e], 1);
    int p = off[e] + slot;
    tok[p] = t;
    wof[p] = rw[t * 4 + k];
  }
}

// ---------------- MoE GEMM: 256x256 tile, BK=64, 8 waves, 8-phase counted-vmcnt schedule ----------------
#define GLL(g, l) __builtin_amdgcn_global_load_lds(                         \
    (const __attribute__((address_space(1))) void*)(g),                    \
    (__attribute__((address_space(3))) void*)(l), 16, 0, 0)

// stage one half-tile (128 rows x 64 cols, 16 KiB) into buf b (0/1); 2 GLL per thread
#define ST_A0(b, ko) { GLL(aP[0] + (ko), ldsc + (b)*65536 +     0 + stDst); GLL(aP[1] + (ko), ldsc + (b)*65536 +  8192 + stDst); }
#define ST_A1(b, ko) { GLL(aP[2] + (ko), ldsc + (b)*65536 + 16384 + stDst); GLL(aP[3] + (ko), ldsc + (b)*65536 + 24576 + stDst); }
#define ST_B0(b, ko) { GLL(bP[0] + (ko), ldsc + (b)*65536 + 32768 + stDst); GLL(bP[1] + (ko), ldsc + (b)*65536 + 40960 + stDst); }
#define ST_B1(b, ko) { GLL(bP[2] + (ko), ldsc + (b)*65536 + 49152 + stDst); GLL(bP[3] + (ko), ldsc + (b)*65536 + 57344 + stDst); }

#define BAR  asm volatile("s_barrier" ::: "memory")
#define WAIT4 asm volatile("s_waitcnt vmcnt(4)" ::: "memory")
#define WAIT0 asm volatile("s_waitcnt vmcnt(0)" ::: "memory")

// read A-quadrant mq (4 m-frags x 2 kk) into af
#define RD_A(Ab, mq) { _Pragma("unroll") for (int i_ = 0; i_ < 4; ++i_) { \
    af[i_][0] = *(const bf16x8*)&(Ab)[((size_t)(wrlr + ((mq)*4 + i_)*16))*64 + c0]; \
    af[i_][1] = *(const bf16x8*)&(Ab)[((size_t)(wrlr + ((mq)*4 + i_)*16))*64 + c1]; } }
// read B-quadrant nq (2 n-frags x 2 kk) into bfr
#define RD_B(Bb, nq) { _Pragma("unroll") for (int j_ = 0; j_ < 2; ++j_) { \
    bfr[(nq)*2 + j_][0] = *(const bf16x8*)&(Bb)[((size_t)(wclr + ((nq)*2 + j_)*16))*64 + c0]; \
    bfr[(nq)*2 + j_][1] = *(const bf16x8*)&(Bb)[((size_t)(wclr + ((nq)*2 + j_)*16))*64 + c1]; } }
// one C-quadrant x K=64: 16 MFMA
#define MMA_Q(mq, nq) { __builtin_amdgcn_s_setprio(1); \
  _Pragma("unroll") for (int kk_ = 0; kk_ < 2; ++kk_) \
  _Pragma("unroll") for (int i_ = 0; i_ < 4; ++i_) \
  _Pragma("unroll") for (int j_ = 0; j_ < 2; ++j_) \
    acc[(mq)*4 + i_][(nq)*2 + j_] = __builtin_amdgcn_mfma_f32_16x16x32_bf16( \
        af[i_][kk_], bfr[(nq)*2 + j_][kk_], acc[(mq)*4 + i_][(nq)*2 + j_], 0, 0, 0); \
  __builtin_amdgcn_s_setprio(0); }

template <int MODE>
__global__ __launch_bounds__(512, 2) void moe_gemm_kernel(
    const unsigned short* __restrict__ A, const unsigned short* __restrict__ Bt,
    const float* __restrict__ bias, const int* __restrict__ cnt,
    const int* __restrict__ off, const int* __restrict__ tok,
    const float* __restrict__ wof, unsigned short* __restrict__ hout,
    float* __restrict__ out) {
  __shared__ unsigned short lds[65536];  // 128 KiB: [2 buf][A 32KB | B 32KB]
  const int bid = blockIdx.x;
  const int e   = bid & 7;        // expert == XCD (T1)
  const int rem = bid >> 3;
  const int bm  = rem & 15;
  const int bn  = rem >> 4;
  const int ne  = cnt[e];
  const int m0  = bm * 256;
  if (m0 >= ne) return;
  const int oe  = off[e];
  const int n0  = bn * 256;
  const int tid = threadIdx.x;
  const int w   = tid >> 6;
  const int l   = tid & 63;

  // staging: LDS linear, global source chunk XOR-swizzled (T2 both-sides).
  const int srow = tid >> 3;                       // row 0..63 within a 64-row round
  const int scg  = ((tid & 7) ^ (srow & 7)) * 8;   // swizzled source chunk, elems
  const unsigned short* aP[4];
  const unsigned short* bP[4];
#pragma unroll
  for (int j = 0; j < 4; ++j) {
    int r = m0 + j * 64 + srow;
    if (r > ne - 1) r = ne - 1;
    if (MODE == 0)
      aP[j] = A + (size_t)tok[oe + r] * 2048 + scg;
    else
      aP[j] = A + (size_t)(oe + r) * 2048 + scg;
    bP[j] = Bt + ((size_t)e * 2048 + n0 + j * 64 + srow) * 2048 + scg;
  }
  char* ldsc = (char*)lds;
  const int stDst = tid * 16;

  const int wr = (w >> 2) * 128;  // 2 waves in M (wave tile 128x64)
  const int wc = (w & 3) * 64;    // 4 waves in N
  const int lr = l & 15;
  const int lq = l >> 4;
  const int cx = lr & 7;
  const int wrlr = wr + lr;
  const int wclr = wc + lr;
  const int c0 = ((0 * 4 + lq) ^ cx) * 8;   // chunk offset (shorts) for kk=0
  const int c1 = ((1 * 4 + lq) ^ cx) * 8;   // kk=1

  const unsigned short* Ab0 = lds;           // buf0 A  [256][64]
  const unsigned short* Bb0 = lds + 16384;   // buf0 B
  const unsigned short* Ab1 = lds + 32768;   // buf1 A
  const unsigned short* Bb1 = lds + 49152;   // buf1 B

  f32x4 acc[8][4];
#pragma unroll
  for (int m = 0; m < 8; ++m)
#pragma unroll
    for (int n = 0; n < 4; ++n) acc[m][n] = (f32x4){0.f, 0.f, 0.f, 0.f};

  // prologue: tile0 -> buf0 (all 4 halves), tile1 -> buf1 (B halves; A halves staged in p0/p1)
  ST_B0(0, 0); ST_B1(0, 0); ST_A0(0, 0); ST_A1(0, 0);
  ST_B0(1, 64); ST_B1(1, 64);
  // R3 fix: drain buf0's 8 loads (leave buf1.B's 4 in flight) + barrier BEFORE
  // the first ds_read of buf0 in phase 0. This was the missing edge -> NaN race.
  WAIT4; BAR;

#pragma unroll 1
  for (int it = 0; it < NITER; ++it) {
    const int ko1 = (2 * it + 1) * 64;
    const int ko2 = (2 * it + 2) * 64;
    const int ko3 = (2 * it + 3) * 64;
    const bool pf = (it < NITER - 1);
    bf16x8 af[4][2], bfr[4][2];

    // ---- phase 0: reads t0 (buf0) quadrant (0,0); stages t1.A0
    ST_A0(1, ko1);
    RD_A(Ab0, 0); RD_B(Bb0, 0);
    BAR; MMA_Q(0, 0); BAR;
    // ---- phase 1: stages t1.A1
    ST_A1(1, ko1);
    RD_B(Bb0, 1);
    BAR; MMA_Q(0, 1); BAR;
    // ---- phase 2: stages t2.B0 (buf0.B free after p1 end-barrier)
    if (pf) ST_B0(0, ko2);
    RD_A(Ab0, 1);
    BAR; MMA_Q(1, 0); BAR;
    // ---- phase 3: stages t2.B1; counted wait covering t1 (t2.B0/B1 stay in flight)
    if (pf) { ST_B1(0, ko2); WAIT4; } else { WAIT0; }
    BAR; MMA_Q(1, 1); BAR;
    // ---- phase 4: reads t1 (buf1) quadrant (0,0); stages t2.A0 (buf0.A free after p2)
    if (pf) ST_A0(0, ko2);
    RD_A(Ab1, 0); RD_B(Bb1, 0);
    BAR; MMA_Q(0, 0); BAR;
    // ---- phase 5: stages t2.A1
    if (pf) ST_A1(0, ko2);
    RD_B(Bb1, 1);
    BAR; MMA_Q(0, 1); BAR;
    // ---- phase 6: stages t3.B0 (buf1.B free after p5)
    if (pf) ST_B0(1, ko3);
    RD_A(Ab1, 1);
    BAR; MMA_Q(1, 0); BAR;
    // ---- phase 7: stages t3.B1; counted wait covering t2 (t3.B0/B1 stay in flight)
    if (pf) { ST_B1(1, ko3); WAIT4; }
    BAR; MMA_Q(1, 1); BAR;
  }

  // epilogue: C/D layout col = lane&15, row = (lane>>4)*4 + j
  const int rj = lq * 4;
  float bvn[4];
#pragma unroll
  for (int n = 0; n < 4; ++n) bvn[n] = bias[e * 2048 + n0 + wc + n * 16 + lr];
#pragma unroll
  for (int m = 0; m < 8; ++m) {
    const int rbase = m0 + wr + m * 16 + rj;
#pragma unroll
    for (int j = 0; j < 4; ++j) {
      const int row = rbase + j;
      if (row < ne) {
        if (MODE == 0) {
#pragma unroll
          for (int n = 0; n < 4; ++n) {
            const int col = n0 + wc + n * 16 + lr;
            float v = acc[m][n][j] + bvn[n];
            float g = 0.5f * v * (1.0f + erff(v * 0.70710678118f));
            hout[(size_t)(oe + row) * 2048 + col] = f2bf(g);
          }
        } else {
          const int p = oe + row;
          const int tk = tok[p];
          const float wf = wof[p];
#pragma unroll
          for (int n = 0; n < 4; ++n) {
            const int col = n0 + wc + n * 16 + lr;
            atomicAdd(&out[(size_t)tk * 2048 + col], wf * (acc[m][n][j] + bvn[n]));
          }
        }
      }
    }
  }
}

extern "C" void kernel_launch(void* const* d_in, const int* in_sizes, int n_in,
                              void* d_out, int out_size, void* d_ws, size_t ws_size,
                              hipStream_t stream) {
  const float* x  = (const float*)d_in[0];
  const float* Wg = (const float*)d_in[1];
  const float* bg = (const float*)d_in[2];
  const float* W1 = (const float*)d_in[3];
  const float* b1 = (const float*)d_in[4];
  const float* W2 = (const float*)d_in[5];
  const float* b2 = (const float*)d_in[6];
  float* out = (float*)d_out;
  float* logits = out + (size_t)T_TOK * DDIM;

  char* ws = (char*)d_ws;
  int* cnt  = (int*)(ws);
  int* off  = (int*)(ws + 32);
  int* fill = (int*)(ws + 64);
  size_t o = 256;
  unsigned short* xb   = (unsigned short*)(ws + o); o += (size_t)T_TOK * DDIM * 2;
  unsigned short* W1t  = (unsigned short*)(ws + o); o += (size_t)NEXP * DDIM * HDIM * 2;
  unsigned short* W2t  = (unsigned short*)(ws + o); o += (size_t)NEXP * DDIM * HDIM * 2;
  unsigned short* hbuf = (unsigned short*)(ws + o); o += (size_t)NPAIR * HDIM * 2;
  float* rw  = (float*)(ws + o); o += (size_t)T_TOK * 4 * 4;
  int*   sel = (int*)(ws + o);   o += (size_t)T_TOK * 4 * 4;
  int*   tok = (int*)(ws + o);   o += (size_t)NPAIR * 4;
  float* wof = (float*)(ws + o); o += (size_t)NPAIR * 4;

  hipMemsetAsync(d_out, 0, (size_t)T_TOK * DDIM * sizeof(float), stream);
  hipMemsetAsync(ws, 0, 256, stream);

  conv_x_kernel<<<(T_TOK * DDIM) / 1024, 256, 0, stream>>>(x, xb);
  transpose_conv_kernel<<<dim3(32, 32, 8), 256, 0, stream>>>(W1, W1t);
  transpose_conv_kernel<<<dim3(32, 32, 8), 256, 0, stream>>>(W2, W2t);
  routing_kernel<<<T_TOK / 4, 256, 0, stream>>>(x, Wg, bg, logits, rw, sel, cnt);
  offsets_kernel<<<1, 64, 0, stream>>>(cnt, off);
  scatter_kernel<<<T_TOK / 256, 256, 0, stream>>>(sel, rw, off, fill, tok, wof);

  moe_gemm_kernel<0><<<dim3(1024), 512, 0, stream>>>(xb, W1t, b1, cnt, off, tok, wof, hbuf, nullptr);
  moe_gemm_kernel<1><<<dim3(1024), 512, 0, stream>>>(hbuf, W2t, b2, cnt, off, tok, wof, nullptr, out);
}